// Round 1
// baseline (140.425 us; speedup 1.0000x reference)
//
#include <hip/hip_runtime.h>
#include <math.h>

#define N_NODES 10000
#define DEG1 33          // DEG + self-loop
#define D_EMB 128
#define F_IN 128
#define BATCH 2

// Kernel 1: h = X @ W  (rows = B*N), plus s = h.a_src, d = h.a_dst per row.
// One 128-thread block per row. X row staged in LDS, broadcast-read as float4.
__global__ __launch_bounds__(128) void gat_h_kernel(
    const float* __restrict__ X, const float* __restrict__ W,
    const float* __restrict__ Wattn,
    float* __restrict__ h, float* __restrict__ s_arr, float* __restrict__ d_arr)
{
    const int r = blockIdx.x;          // 0 .. B*N-1
    const int t = threadIdx.x;         // 0..127 (output column)
    __shared__ float xs[F_IN];
    __shared__ float red[4];
    xs[t] = X[r * F_IN + t];
    __syncthreads();

    float acc = 0.f;
    #pragma unroll
    for (int k = 0; k < F_IN; k += 4) {
        float4 xv = *(const float4*)&xs[k];   // wave-uniform address -> broadcast
        acc = fmaf(xv.x, W[(k + 0) * D_EMB + t], acc);
        acc = fmaf(xv.y, W[(k + 1) * D_EMB + t], acc);
        acc = fmaf(xv.z, W[(k + 2) * D_EMB + t], acc);
        acc = fmaf(xv.w, W[(k + 3) * D_EMB + t], acc);
    }
    h[r * D_EMB + t] = acc;

    // per-row dots with a_src / a_dst (128-wide reduction, 2 waves)
    float sv = acc * Wattn[t];
    float dv = acc * Wattn[D_EMB + t];
    #pragma unroll
    for (int off = 32; off > 0; off >>= 1) {
        sv += __shfl_down(sv, off, 64);
        dv += __shfl_down(dv, off, 64);
    }
    if ((t & 63) == 0) { red[t >> 6] = sv; red[2 + (t >> 6)] = dv; }
    __syncthreads();
    if (t == 0) {
        s_arr[r] = red[0] + red[1];
        d_arr[r] = red[2] + red[3];
    }
}

// Kernel 2: per-node edge phase. Edges are sorted by src with exactly 33
// edges per node -> contiguous segment [i*33, (i+1)*33). denom uses batch 0
// only; inv_denom factors out of both batches' aggregates.
__global__ __launch_bounds__(128) void gat_agg_kernel(
    const float* __restrict__ h, const float* __restrict__ s_arr,
    const float* __restrict__ d_arr, const int* __restrict__ edges,
    float* __restrict__ out)
{
    const int i = blockIdx.x;   // node
    const int t = threadIdx.x;  // 0..127 (embedding dim)
    __shared__ int dsts[DEG1];
    __shared__ float sc[2][DEG1];
    __shared__ float inv_denom;

    if (t < 2 * DEG1) {
        const int b = (t >= DEG1) ? 1 : 0;
        const int j = t - b * DEG1;
        const int dst = edges[(i * DEG1 + j) * 2 + 1];
        if (b == 0) dsts[j] = dst;
        float x = s_arr[b * N_NODES + i] + d_arr[b * N_NODES + dst];
        x = (x >= 0.f) ? x : 0.2f * x;        // leaky_relu(0.2)
        x = fminf(fmaxf(x, -2.f), 2.f);       // clip
        sc[b][j] = expf(x);
    }
    __syncthreads();

    if (t < 64) {   // wave 0 reduces batch-0 scores for the denom
        float v = (t < DEG1) ? sc[0][t] : 0.f;
        #pragma unroll
        for (int off = 32; off > 0; off >>= 1) v += __shfl_down(v, off, 64);
        if (t == 0) inv_denom = 1.f / v;
    }
    __syncthreads();

    float acc = 0.f;
    #pragma unroll
    for (int j = 0; j < DEG1; ++j) {
        const int dd = dsts[j];
        acc = fmaf(sc[0][j], h[dd * D_EMB + t], acc);
        acc = fmaf(sc[1][j], h[(N_NODES + dd) * D_EMB + t], acc);
    }
    acc *= inv_denom;
    out[i * D_EMB + t] = acc;                       // batch 0
    out[(N_NODES + i) * D_EMB + t] = acc;           // batch 1 (broadcast copy)
}

extern "C" void kernel_launch(void* const* d_in, const int* in_sizes, int n_in,
                              void* d_out, int out_size, void* d_ws, size_t ws_size,
                              hipStream_t stream) {
    const float* X     = (const float*)d_in[0];   // (2, 10000, 128) fp32
    const float* W     = (const float*)d_in[1];   // (128, 128) fp32
    const float* Wattn = (const float*)d_in[2];   // (256, 1) fp32
    const int*   edges = (const int*)d_in[3];     // (330000, 2) int32
    float* out = (float*)d_out;                   // (2, 10000, 128) fp32

    float* h     = (float*)d_ws;                          // B*N*D floats
    float* s_arr = h + (size_t)BATCH * N_NODES * D_EMB;   // B*N floats
    float* d_arr = s_arr + (size_t)BATCH * N_NODES;       // B*N floats

    gat_h_kernel<<<BATCH * N_NODES, 128, 0, stream>>>(X, W, Wattn, h, s_arr, d_arr);
    gat_agg_kernel<<<N_NODES, 128, 0, stream>>>(h, s_arr, d_arr, edges, out);
}

// Round 2
// 122.413 us; speedup vs baseline: 1.1471x; 1.1471x over previous
//
#include <hip/hip_runtime.h>
#include <math.h>

#define N_NODES 10000
#define DEG1 33          // DEG + self-loop
#define D_EMB 128
#define F_IN 128
#define BATCH 2
#define TM 32            // rows per block (kernel 1)
#define KC 64            // K-chunk staged in LDS

// Kernel 1: h = X @ W  (20000 x 128 x 128 fp32), plus s = h.a_src, d = h.a_dst.
// 256-thread block computes 32 rows x 128 cols; each thread a 4x4 register tile.
__global__ __launch_bounds__(256) void gat_h_kernel(
    const float* __restrict__ X, const float* __restrict__ W,
    const float* __restrict__ Wattn,
    float* __restrict__ h, float* __restrict__ s_arr, float* __restrict__ d_arr)
{
    const int t = threadIdx.x;
    const int row0 = blockIdx.x * TM;
    __shared__ float ws[KC * D_EMB];   // ws[k*128 + c], one K-chunk of W
    __shared__ float xs[TM * KC];      // xs[r*64 + k]

    const int c0 = (t & 31) * 4;       // this thread's 4 cols
    const int r0 = (t >> 5) * 4;       // this thread's 4 rows

    float acc[4][4] = {};

    for (int kc = 0; kc < F_IN / KC; ++kc) {
        const int k0 = kc * KC;
        // stage W chunk: 64 k-rows x 128 cols (coalesced read, linear write)
        #pragma unroll
        for (int m = 0; m < (KC * D_EMB) / 256; ++m) {
            const int idx = t + 256 * m;
            ws[idx] = W[(k0 + (idx >> 7)) * D_EMB + (idx & 127)];
        }
        // stage X tile: 32 rows x 64 k
        #pragma unroll
        for (int m = 0; m < (TM * KC) / 256; ++m) {
            const int idx = t + 256 * m;
            const int r = idx >> 6, k = idx & 63;
            xs[r * KC + k] = X[(size_t)(row0 + r) * F_IN + k0 + k];
        }
        __syncthreads();

        #pragma unroll 4
        for (int k = 0; k < KC; k += 4) {
            float4 xv[4], wv[4];
            #pragma unroll
            for (int ri = 0; ri < 4; ++ri)
                xv[ri] = *(const float4*)&xs[(r0 + ri) * KC + k];
            #pragma unroll
            for (int kk = 0; kk < 4; ++kk)
                wv[kk] = *(const float4*)&ws[(k + kk) * D_EMB + c0];
            #pragma unroll
            for (int ri = 0; ri < 4; ++ri) {
                #pragma unroll
                for (int ci = 0; ci < 4; ++ci) {
                    acc[ri][ci] = fmaf(xv[ri].x, ((const float*)&wv[0])[ci], acc[ri][ci]);
                    acc[ri][ci] = fmaf(xv[ri].y, ((const float*)&wv[1])[ci], acc[ri][ci]);
                    acc[ri][ci] = fmaf(xv[ri].z, ((const float*)&wv[2])[ci], acc[ri][ci]);
                    acc[ri][ci] = fmaf(xv[ri].w, ((const float*)&wv[3])[ci], acc[ri][ci]);
                }
            }
        }
        __syncthreads();
    }

    // store h (float4 per row)
    #pragma unroll
    for (int ri = 0; ri < 4; ++ri) {
        float4 v = make_float4(acc[ri][0], acc[ri][1], acc[ri][2], acc[ri][3]);
        *(float4*)&h[(size_t)(row0 + r0 + ri) * D_EMB + c0] = v;
    }

    // s/d: per-thread partials over its 4 cols, reduce across the 32 lanes
    // of each half-wave (t>>5 group lives in one 32-lane segment).
    const float4 as = *(const float4*)&Wattn[c0];
    const float4 ad = *(const float4*)&Wattn[D_EMB + c0];
    #pragma unroll
    for (int ri = 0; ri < 4; ++ri) {
        float sv = acc[ri][0] * as.x + acc[ri][1] * as.y + acc[ri][2] * as.z + acc[ri][3] * as.w;
        float dv = acc[ri][0] * ad.x + acc[ri][1] * ad.y + acc[ri][2] * ad.z + acc[ri][3] * ad.w;
        #pragma unroll
        for (int off = 16; off > 0; off >>= 1) {
            sv += __shfl_down(sv, off, 32);
            dv += __shfl_down(dv, off, 32);
        }
        if ((t & 31) == 0) {
            s_arr[row0 + r0 + ri] = sv;
            d_arr[row0 + r0 + ri] = dv;
        }
    }
}

// Kernel 2: per-node edge phase. 33 edges/node contiguous (sorted by src).
// denom from batch 0 only; inv_denom factors out. float4 gathers, 4
// independent 32-lane accumulation streams per node.
__global__ __launch_bounds__(128) void gat_agg_kernel(
    const float* __restrict__ h, const float* __restrict__ s_arr,
    const float* __restrict__ d_arr, const int* __restrict__ edges,
    float* __restrict__ out)
{
    const int i = blockIdx.x;   // node
    const int t = threadIdx.x;
    __shared__ int dsts[DEG1];
    __shared__ float sc[2][DEG1];
    __shared__ float inv_denom;
    __shared__ float4 red[4][32];

    if (t < 2 * DEG1) {
        const int b = (t >= DEG1) ? 1 : 0;
        const int j = t - b * DEG1;
        const int dst = edges[(i * DEG1 + j) * 2 + 1];
        if (b == 0) dsts[j] = dst;
        float x = s_arr[b * N_NODES + i] + d_arr[b * N_NODES + dst];
        x = (x >= 0.f) ? x : 0.2f * x;        // leaky_relu(0.2)
        x = fminf(fmaxf(x, -2.f), 2.f);       // clip
        sc[b][j] = expf(x);
    }
    __syncthreads();

    if (t < 64) {   // wave 0 reduces batch-0 scores for the denom
        float v = (t < DEG1) ? sc[0][t] : 0.f;
        #pragma unroll
        for (int off = 32; off > 0; off >>= 1) v += __shfl_down(v, off, 64);
        if (t == 0) inv_denom = 1.f / v;
    }

    const int lane = t & 31;
    const int q = t >> 5;          // quarter 0..3
    const int b = q >> 1;          // batch
    const int half = q & 1;        // even/odd edges
    const float4* __restrict__ h4 = (const float4*)h + (size_t)b * N_NODES * (D_EMB / 4);
    float4 acc = make_float4(0.f, 0.f, 0.f, 0.f);
    #pragma unroll
    for (int jj = 0; jj < (DEG1 + 1) / 2; ++jj) {
        const int j = half + 2 * jj;
        if (j < DEG1) {
            const float w = sc[b][j];
            const float4 hv = h4[(size_t)dsts[j] * (D_EMB / 4) + lane];
            acc.x = fmaf(w, hv.x, acc.x);
            acc.y = fmaf(w, hv.y, acc.y);
            acc.z = fmaf(w, hv.z, acc.z);
            acc.w = fmaf(w, hv.w, acc.w);
        }
    }
    red[q][lane] = acc;
    __syncthreads();

    if (t < 32) {
        const float4 a0 = red[0][t], a1 = red[1][t], a2 = red[2][t], a3 = red[3][t];
        const float s = inv_denom;
        float4 o;
        o.x = (a0.x + a1.x + a2.x + a3.x) * s;
        o.y = (a0.y + a1.y + a2.y + a3.y) * s;
        o.z = (a0.z + a1.z + a2.z + a3.z) * s;
        o.w = (a0.w + a1.w + a2.w + a3.w) * s;
        float4* o4 = (float4*)out;
        o4[(size_t)i * (D_EMB / 4) + t] = o;                     // batch 0
        o4[(size_t)(N_NODES + i) * (D_EMB / 4) + t] = o;         // batch 1
    }
}

extern "C" void kernel_launch(void* const* d_in, const int* in_sizes, int n_in,
                              void* d_out, int out_size, void* d_ws, size_t ws_size,
                              hipStream_t stream) {
    const float* X     = (const float*)d_in[0];   // (2, 10000, 128) fp32
    const float* W     = (const float*)d_in[1];   // (128, 128) fp32
    const float* Wattn = (const float*)d_in[2];   // (256, 1) fp32
    const int*   edges = (const int*)d_in[3];     // (330000, 2) int32
    float* out = (float*)d_out;                   // (2, 10000, 128) fp32

    float* h     = (float*)d_ws;                          // B*N*D floats
    float* s_arr = h + (size_t)BATCH * N_NODES * D_EMB;   // B*N floats
    float* d_arr = s_arr + (size_t)BATCH * N_NODES;       // B*N floats

    gat_h_kernel<<<(BATCH * N_NODES) / TM, 256, 0, stream>>>(X, W, Wattn, h, s_arr, d_arr);
    gat_agg_kernel<<<N_NODES, 128, 0, stream>>>(h, s_arr, d_arr, edges, out);
}

// Round 3
// 93.231 us; speedup vs baseline: 1.5062x; 1.3130x over previous
//
#include <hip/hip_runtime.h>
#include <math.h>

#define N_NODES 10000
#define DEG1 33          // DEG + self-loop
#define D_EMB 128
#define F_IN 128
#define BATCH 2

typedef short s8v  __attribute__((ext_vector_type(8)));
typedef float f4v  __attribute__((ext_vector_type(4)));

// fp32 -> bf16 round-to-nearest-even (no NaN special-case; inputs are normal)
static __device__ __forceinline__ unsigned short f2bf(float f) {
    unsigned int x = __float_as_uint(f);
    unsigned int r = (x + 0x7fffu + ((x >> 16) & 1u)) >> 16;
    return (unsigned short)r;
}
static __device__ __forceinline__ float bf_lo(unsigned int u) { return __uint_as_float(u << 16); }
static __device__ __forceinline__ float bf_hi(unsigned int u) { return __uint_as_float(u & 0xffff0000u); }

// ---------------------------------------------------------------------------
// Kernel 0 (prep): pack W (128x128 fp32) into bf16 B-fragments for
// mfma_f32_16x16x32_bf16. Fragment element j of lane l, col-tile c, k-step s:
//   B[k = s*32 + (l>>4)*8 + j][n = c*16 + (l&15)]
// Output layout: wtf[((c*4+s)*64 + l)*8 + j]  (16B per lane -> coalesced
// dwordx4 loads in the GEMM). 8 blocks, one per col-tile c.
// ---------------------------------------------------------------------------
__global__ __launch_bounds__(256) void gat_prep_kernel(
    const float* __restrict__ W, unsigned short* __restrict__ wtf)
{
    const int c = blockIdx.x;
    const int t = threadIdx.x;
    __shared__ float xs[128 * 16];   // W[:, c*16 .. c*16+16)
    #pragma unroll
    for (int r = 0; r < 8; ++r) {
        const int k = r * 16 + (t >> 4);
        const int n = t & 15;
        xs[k * 16 + n] = W[k * 128 + c * 16 + n];
    }
    __syncthreads();
    const int s = t >> 6;    // k-step 0..3
    const int l = t & 63;    // lane
    s8v frag;
    #pragma unroll
    for (int j = 0; j < 8; ++j) {
        const int k = s * 32 + (l >> 4) * 8 + j;
        frag[j] = (short)f2bf(xs[k * 16 + (l & 15)]);
    }
    *(s8v*)&wtf[(((size_t)c * 4 + s) * 64 + l) * 8] = frag;
}

// ---------------------------------------------------------------------------
// Kernel 1: h = X @ W via bf16 MFMA. Each wave: 16 rows x 128 cols.
// No LDS, no barriers: A-frags straight from global X (line-coalesced),
// B-frags from the prepacked wtf (perfectly coalesced, L2-hot).
// Also computes s = h.a_src, d = h.a_dst from the fp32 accumulators.
// h stored bf16, batch-interleaved: h[(n*2+b)*128 + col].
// ---------------------------------------------------------------------------
__global__ __launch_bounds__(256) void gat_h_kernel(
    const float* __restrict__ X, const unsigned short* __restrict__ wtf,
    const float* __restrict__ Wattn,
    unsigned short* __restrict__ hb, float* __restrict__ s_arr, float* __restrict__ d_arr)
{
    const int w = blockIdx.x * 4 + (threadIdx.x >> 6);   // global wave id
    if (w >= (BATCH * N_NODES) / 16) return;             // 1250 waves exactly
    const int lane = threadIdx.x & 63;
    const int quad = lane >> 4;
    const int mrow = lane & 15;
    const int row0 = w * 16;

    f4v acc[8];
    #pragma unroll
    for (int c = 0; c < 8; ++c) acc[c] = (f4v){0.f, 0.f, 0.f, 0.f};

    const float* xrow = X + (size_t)(row0 + mrow) * F_IN;
    #pragma unroll
    for (int s = 0; s < 4; ++s) {
        const int k0 = s * 32 + quad * 8;
        const float4 xa = *(const float4*)&xrow[k0];
        const float4 xbv = *(const float4*)&xrow[k0 + 4];
        s8v a;
        a[0] = (short)f2bf(xa.x);  a[1] = (short)f2bf(xa.y);
        a[2] = (short)f2bf(xa.z);  a[3] = (short)f2bf(xa.w);
        a[4] = (short)f2bf(xbv.x); a[5] = (short)f2bf(xbv.y);
        a[6] = (short)f2bf(xbv.z); a[7] = (short)f2bf(xbv.w);
        #pragma unroll
        for (int c = 0; c < 8; ++c) {
            const s8v b = *(const s8v*)&wtf[(((size_t)c * 4 + s) * 64 + lane) * 8];
            acc[c] = __builtin_amdgcn_mfma_f32_16x16x32_bf16(a, b, acc[c], 0, 0, 0);
        }
    }

    // ---- store h (bf16, interleaved (n, b)) ----
    const int b = (row0 >= N_NODES) ? 1 : 0;
    #pragma unroll
    for (int r = 0; r < 4; ++r) {
        const int R = row0 + quad * 4 + r;
        const int n = R - b * N_NODES;
        unsigned short* dst = &hb[((size_t)n * 2 + b) * D_EMB + mrow];
        #pragma unroll
        for (int c = 0; c < 8; ++c)
            dst[c * 16] = f2bf(acc[c][r]);
    }

    // ---- s/d dots: reduce across the 16 lanes (mrow) of each quad ----
    float as[8], ad[8];
    #pragma unroll
    for (int c = 0; c < 8; ++c) {
        as[c] = Wattn[c * 16 + mrow];
        ad[c] = Wattn[D_EMB + c * 16 + mrow];
    }
    #pragma unroll
    for (int r = 0; r < 4; ++r) {
        float sv = 0.f, dv = 0.f;
        #pragma unroll
        for (int c = 0; c < 8; ++c) {
            sv = fmaf(acc[c][r], as[c], sv);
            dv = fmaf(acc[c][r], ad[c], dv);
        }
        #pragma unroll
        for (int off = 1; off < 16; off <<= 1) {
            sv += __shfl_xor(sv, off, 16);
            dv += __shfl_xor(dv, off, 16);
        }
        if (mrow == 0) {
            const int R = row0 + quad * 4 + r;
            s_arr[R] = sv;
            d_arr[R] = dv;
        }
    }
}

// ---------------------------------------------------------------------------
// Kernel 2: edge phase. Block = 128 threads = 2 waves, one node; wave = batch.
// Scores + denom (batch 0 only; inv_denom factors out of both batches).
// Gather: per edge one coalesced 256B bf16 row read (uint = bf16x2 per lane).
// ---------------------------------------------------------------------------
__global__ __launch_bounds__(128) void gat_agg_kernel(
    const unsigned int* __restrict__ hb32, const float* __restrict__ s_arr,
    const float* __restrict__ d_arr, const int* __restrict__ edges,
    float* __restrict__ out)
{
    const int i = blockIdx.x;
    const int t = threadIdx.x;
    const int b = t >> 6;        // batch (wave id)
    const int lane = t & 63;

    __shared__ int dsts[DEG1];
    __shared__ float scs[2][DEG1];
    __shared__ float inv_denom;
    __shared__ float red[2][2 * 64];

    float v = 0.f;
    if (lane < DEG1) {
        const int dst = edges[((size_t)i * DEG1 + lane) * 2 + 1];
        const float x0 = s_arr[b * N_NODES + i] + d_arr[b * N_NODES + dst];
        float x = (x0 >= 0.f) ? x0 : 0.2f * x0;       // leaky_relu(0.2)
        x = fminf(fmaxf(x, -2.f), 2.f);               // clip
        const float sc = __expf(x);
        scs[b][lane] = sc;
        if (b == 0) { dsts[lane] = dst; v = sc; }
    }
    #pragma unroll
    for (int off = 32; off > 0; off >>= 1) v += __shfl_down(v, off, 64);
    if (t == 0) inv_denom = 1.f / v;
    __syncthreads();

    float ax = 0.f, ay = 0.f;
    #pragma unroll
    for (int j = 0; j < DEG1; ++j) {
        const int dd = dsts[j];
        const float wgt = scs[b][j];
        const unsigned int hv = hb32[((size_t)dd * 2 + b) * (D_EMB / 2) + lane];
        ax = fmaf(wgt, bf_lo(hv), ax);
        ay = fmaf(wgt, bf_hi(hv), ay);
    }
    red[b][2 * lane] = ax;
    red[b][2 * lane + 1] = ay;
    __syncthreads();

    const float inv = inv_denom;
    float2 o;
    o.x = (red[0][2 * lane] + red[1][2 * lane]) * inv;
    o.y = (red[0][2 * lane + 1] + red[1][2 * lane + 1]) * inv;
    // identical output for both batches; wave b stores batch b's copy
    *(float2*)&out[((size_t)b * N_NODES + i) * D_EMB + 2 * lane] = o;
}

extern "C" void kernel_launch(void* const* d_in, const int* in_sizes, int n_in,
                              void* d_out, int out_size, void* d_ws, size_t ws_size,
                              hipStream_t stream) {
    const float* X     = (const float*)d_in[0];   // (2, 10000, 128) fp32
    const float* W     = (const float*)d_in[1];   // (128, 128) fp32
    const float* Wattn = (const float*)d_in[2];   // (256, 1) fp32
    const int*   edges = (const int*)d_in[3];     // (330000, 2) int32
    float* out = (float*)d_out;                   // (2, 10000, 128) fp32

    unsigned short* wtf = (unsigned short*)d_ws;                 // 16384 bf16 = 32KB
    unsigned short* hb  = wtf + 16384;                           // 2*10000*128 bf16
    float* s_arr = (float*)(hb + (size_t)BATCH * N_NODES * D_EMB);
    float* d_arr = s_arr + BATCH * N_NODES;

    gat_prep_kernel<<<8, 256, 0, stream>>>(W, wtf);
    gat_h_kernel<<<313, 256, 0, stream>>>(X, wtf, Wattn, hb, s_arr, d_arr);
    gat_agg_kernel<<<N_NODES, 128, 0, stream>>>((const unsigned int*)hb, s_arr, d_arr, edges, out);
}